// Round 1
// baseline (287.660 us; speedup 1.0000x reference)
//
#include <hip/hip_runtime.h>

// ---------------------------------------------------------------------------
// CirculantLinear: out = X · Wᵀ where W[o][i] = eig[o/4][i/4][(o%4 - i%4) & 3]
// B = IN = OUT = 4096, MINI_BLOCK = 4, gy = gx = 1024.
// Strategy: bf16 MFMA GEMM (m97 structure). Pre-pass builds bf16 X and W in
// workspace (needs 64 MiB of d_ws).
// ---------------------------------------------------------------------------

typedef __attribute__((ext_vector_type(8))) short bf16x8_t;   // 8 bf16 = 4 VGPRs
typedef __attribute__((ext_vector_type(4))) float f32x4_t;    // MFMA accumulator

#define NDIM 4096
#define TILE 128
#define BK 32

// fp32 -> bf16 round-to-nearest-even (inputs are normal gaussians; no NaN care)
__device__ __forceinline__ unsigned short f2bf(float f) {
    unsigned int u = __builtin_bit_cast(unsigned int, f);
    u += 0x7fffu + ((u >> 16) & 1u);
    return (unsigned short)(u >> 16);
}

// async global -> LDS, 16 bytes per lane (global_load_lds_dwordx4)
__device__ __forceinline__ void async_copy16(const void* g, void* l) {
    __builtin_amdgcn_global_load_lds(
        (const __attribute__((address_space(1))) void*)g,
        (__attribute__((address_space(3))) void*)l,
        16, 0, 0);
}

// ---- pre-pass 1: X fp32 -> bf16 -------------------------------------------
__global__ __launch_bounds__(256) void cvt_x_kernel(const float4* __restrict__ x,
                                                    ushort4* __restrict__ xb) {
    int i = blockIdx.x * 256 + threadIdx.x;     // 4096*4096/4 elements
    float4 v = x[i];
    ushort4 o;
    o.x = f2bf(v.x); o.y = f2bf(v.y); o.z = f2bf(v.z); o.w = f2bf(v.w);
    xb[i] = o;
}

// ---- pre-pass 2: expand eigens -> circulant W (bf16, N x K row-major) -----
// one thread per (y, x) 4x4 block; writes 4 rows of 4 bf16 each
__global__ __launch_bounds__(256) void build_w_kernel(const float4* __restrict__ eig,
                                                      unsigned short* __restrict__ w) {
    int idx = blockIdx.x * 256 + threadIdx.x;   // 0 .. 1024*1024-1
    int y = idx >> 10;
    int x = idx & 1023;
    float4 e4 = eig[idx];
    float ev[4] = {e4.x, e4.y, e4.z, e4.w};
    unsigned short bv[4];
#pragma unroll
    for (int i = 0; i < 4; ++i) bv[i] = f2bf(ev[i]);
#pragma unroll
    for (int r = 0; r < 4; ++r) {               // r = o & 3
        ushort4 o;
        o.x = bv[(r - 0) & 3];
        o.y = bv[(r - 1) & 3];
        o.z = bv[(r - 2) & 3];
        o.w = bv[(r - 3) & 3];
        *(ushort4*)&w[(size_t)(y * 4 + r) * NDIM + x * 4] = o;
    }
}

// ---- main GEMM: C[m][n] = sum_k A[m][k] * B[n][k]  (A=X bf16, B=W bf16) ---
// 128x128 tile per 256-thread block (4 waves in 2x2, each wave 64x64 via
// 4x4 MFMA 16x16x32 tiles). Single-buffered LDS, global_load_lds staging.
__global__ __launch_bounds__(256, 2) void gemm_bt_kernel(
        const unsigned short* __restrict__ A,   // 4096 x 4096 bf16 (row-major)
        const unsigned short* __restrict__ B,   // 4096 x 4096 bf16 (row-major, = Wᵀ input)
        float* __restrict__ C) {
    __shared__ unsigned short lA[TILE * BK];    // 8 KiB
    __shared__ unsigned short lB[TILE * BK];    // 8 KiB

    const int t    = threadIdx.x;
    const int lane = t & 63;
    const int w    = t >> 6;                    // wave 0..3
    const int wm   = (w >> 1) * 64;             // wave row offset in tile
    const int wn   = (w & 1) * 64;              // wave col offset in tile
    const int lr   = lane & 15;
    const int quad = lane >> 4;

    const int blkM = blockIdx.y;
    const int blkN = blockIdx.x;

    // staging: thread t loads 8 bf16 (16 B); 2 calls cover a 128x32 tile
    const int e0 = t * 8;                       // element offset, call 0
    const int r0 = e0 >> 5;                     // row 0..63
    const int c0 = e0 & 31;                     // col 0..31

    const unsigned short* pa0 = A + (size_t)(blkM * TILE + r0) * NDIM + c0;
    const unsigned short* pa1 = pa0 + (size_t)64 * NDIM;
    const unsigned short* pb0 = B + (size_t)(blkN * TILE + r0) * NDIM + c0;
    const unsigned short* pb1 = pb0 + (size_t)64 * NDIM;

    unsigned short* dA0 = &lA[e0];
    unsigned short* dA1 = &lA[2048 + e0];
    unsigned short* dB0 = &lB[e0];
    unsigned short* dB1 = &lB[2048 + e0];

    // fragment read base: row (wm|wn)+mt*16+lr, cols quad*8..quad*8+7
    const unsigned short* la0 = &lA[(wm + lr) * BK + quad * 8];
    const unsigned short* lb0 = &lB[(wn + lr) * BK + quad * 8];

    f32x4_t acc[4][4] = {};

    for (int k0 = 0; k0 < NDIM; k0 += BK) {
        async_copy16(pa0 + k0, dA0);
        async_copy16(pa1 + k0, dA1);
        async_copy16(pb0 + k0, dB0);
        async_copy16(pb1 + k0, dB1);
        asm volatile("s_waitcnt vmcnt(0)" ::: "memory");
        __syncthreads();

        bf16x8_t af[4], bfr[4];
#pragma unroll
        for (int i = 0; i < 4; ++i)
            af[i] = *(const bf16x8_t*)(la0 + i * 16 * BK);
#pragma unroll
        for (int i = 0; i < 4; ++i)
            bfr[i] = *(const bf16x8_t*)(lb0 + i * 16 * BK);

#pragma unroll
        for (int mt = 0; mt < 4; ++mt)
#pragma unroll
            for (int nt = 0; nt < 4; ++nt)
                acc[mt][nt] = __builtin_amdgcn_mfma_f32_16x16x32_bf16(
                    af[mt], bfr[nt], acc[mt][nt], 0, 0, 0);

        __syncthreads();
    }

    // epilogue: C/D layout col = lane&15, row = quad*4 + reg
    const int orow0 = blkM * TILE + wm + quad * 4;
    const int ocol0 = blkN * TILE + wn + lr;
#pragma unroll
    for (int mt = 0; mt < 4; ++mt) {
#pragma unroll
        for (int r = 0; r < 4; ++r) {
            float* dst = C + (size_t)(orow0 + mt * 16 + r) * NDIM + ocol0;
#pragma unroll
            for (int nt = 0; nt < 4; ++nt)
                dst[nt * 16] = acc[mt][nt][r];
        }
    }
}

extern "C" void kernel_launch(void* const* d_in, const int* in_sizes, int n_in,
                              void* d_out, int out_size, void* d_ws, size_t ws_size,
                              hipStream_t stream) {
    const float* x   = (const float*)d_in[0];   // (4096, 4096) fp32
    const float* eig = (const float*)d_in[1];   // (1024, 1024, 4) fp32
    float* out = (float*)d_out;                 // (4096, 4096) fp32

    unsigned short* Xb = (unsigned short*)d_ws;                    // 32 MiB
    unsigned short* Wb = Xb + (size_t)NDIM * NDIM;                 // 32 MiB

    // X -> bf16
    cvt_x_kernel<<<(NDIM * NDIM / 4) / 256, 256, 0, stream>>>(
        (const float4*)x, (ushort4*)Xb);
    // eigens -> bf16 circulant weight (row-major N x K)
    build_w_kernel<<<(1024 * 1024) / 256, 256, 0, stream>>>(
        (const float4*)eig, Wb);

    dim3 grid(NDIM / TILE, NDIM / TILE);        // 32 x 32 blocks
    gemm_bt_kernel<<<grid, 256, 0, stream>>>(Xb, Wb, out);
}

// Round 2
// 227.716 us; speedup vs baseline: 1.2632x; 1.2632x over previous
//
#include <hip/hip_runtime.h>

// ---------------------------------------------------------------------------
// CirculantLinear via length-4 rfft decomposition:
//   out[b, 4y+n] = irfft_n( sum_x rfft(eig[y,x,:]) * rfft(x_blk[b,x,:]) )
// Bins: k=0 (real), k=1 (complex), k=2 (real) -> 4 real GEMMs, 51.5 GFLOP
// vs 137.4 GFLOP dense. GEMMs use the m97 bf16 MFMA structure.
//
// ws layout:  [0, 32MiB)  X' bf16 4096x4096, columns [X0|Xr|Xi|X2] (1024 each)
//             [32, 44MiB) B  bf16 segments: B0(1024x1024), B1r(1024x2048),
//                                           B1i(1024x2048), B2(1024x1024)
// d_out used as scratch for GEMM outputs [O0|Or|Oi|O2] (fp32), then the
// post kernel transforms it in place (row-exclusive blocks).
// ---------------------------------------------------------------------------

typedef __attribute__((ext_vector_type(8))) short bf16x8_t;   // MFMA A/B frag
typedef __attribute__((ext_vector_type(4))) float f32x4_t;    // MFMA acc
typedef __attribute__((ext_vector_type(8))) unsigned short u16x8;

#define NDIM 4096
#define TILE 128
#define BK 32

__device__ __forceinline__ unsigned short f2bf(float f) {
    unsigned int u = __builtin_bit_cast(unsigned int, f);
    u += 0x7fffu + ((u >> 16) & 1u);
    return (unsigned short)(u >> 16);
}

__device__ __forceinline__ void async_copy16(const void* g, void* l) {
    __builtin_amdgcn_global_load_lds(
        (const __attribute__((address_space(1))) void*)g,
        (__attribute__((address_space(3))) void*)l,
        16, 0, 0);
}

// ---- k1: X (fp32) -> X' bf16, columns [X0|Xr|Xi|X2] -----------------------
// thread: one row b, 8 consecutive mini-blocks. 128 threads/row.
__global__ __launch_bounds__(256) void fwd_x_kernel(const float* __restrict__ x,
                                                    unsigned short* __restrict__ xp) {
    int gid = blockIdx.x * 256 + threadIdx.x;    // 0 .. 4096*128-1
    int b   = gid >> 7;
    int j0  = (gid & 127) * 8;                   // mini-block index
    const float4* src = (const float4*)(x + (size_t)b * NDIM + j0 * 4);
    u16x8 s0, sr, si, s2;
#pragma unroll
    for (int i = 0; i < 8; ++i) {
        float4 v = src[i];
        s0[i] = f2bf(v.x + v.y + v.z + v.w);
        sr[i] = f2bf(v.x - v.z);
        si[i] = f2bf(v.w - v.y);
        s2[i] = f2bf(v.x - v.y + v.z - v.w);
    }
    unsigned short* dst = xp + (size_t)b * NDIM + j0;
    *(u16x8*)(dst + 0)    = s0;
    *(u16x8*)(dst + 1024) = sr;
    *(u16x8*)(dst + 2048) = si;
    *(u16x8*)(dst + 3072) = s2;
}

// ---- k2: eigens (gy,gx,4) fp32 -> packed bf16 B segments ------------------
__global__ __launch_bounds__(256) void build_b_kernel(const float* __restrict__ eig,
                                                      unsigned short* __restrict__ B) {
    int gid = blockIdx.x * 256 + threadIdx.x;    // 0 .. 1024*128-1
    int y   = gid >> 7;
    int x0  = (gid & 127) * 8;
    const float4* src = (const float4*)(eig + ((size_t)y * 1024 + x0) * 4);
    u16x8 e0, er, ei, nei, e2;
#pragma unroll
    for (int i = 0; i < 8; ++i) {
        float4 v = src[i];
        e0[i]  = f2bf(v.x + v.y + v.z + v.w);
        float r = v.x - v.z, s = v.w - v.y;
        er[i]  = f2bf(r);
        ei[i]  = f2bf(s);
        nei[i] = f2bf(-s);
        e2[i]  = f2bf(v.x - v.y + v.z - v.w);
    }
    // seg0: B0 (1024x1024)
    *(u16x8*)(B + (size_t)y * 1024 + x0) = e0;
    // seg1: B1r (1024x2048) = [Er | -Ei]
    unsigned short* b1r = B + 1048576 + (size_t)y * 2048;
    *(u16x8*)(b1r + x0)        = er;
    *(u16x8*)(b1r + 1024 + x0) = nei;
    // seg2: B1i (1024x2048) = [Ei | Er]
    unsigned short* b1i = B + 3145728 + (size_t)y * 2048;
    *(u16x8*)(b1i + x0)        = ei;
    *(u16x8*)(b1i + 1024 + x0) = er;
    // seg3: B2 (1024x1024)
    *(u16x8*)(B + 5242880 + (size_t)y * 1024 + x0) = e2;
}

// ---- k3: segmented GEMM, m97 structure ------------------------------------
// blockIdx.x in [0,32): seg = x>>3 selects {O0,Or,Oi,O2}; 8 N-blocks each.
__global__ __launch_bounds__(256, 2) void gemm_seg_kernel(
        const unsigned short* __restrict__ A,   // X' 4096x4096 bf16
        const unsigned short* __restrict__ B,   // packed segments
        float* __restrict__ C) {                // d_out as [O0|Or|Oi|O2] fp32
    __shared__ unsigned short lA[TILE * BK];
    __shared__ unsigned short lB[TILE * BK];

    const int Ks[4]   = {1024, 2048, 2048, 1024};
    const int Aoff[4] = {0, 1024, 1024, 3072};
    const size_t Boff[4] = {0u, 1048576u, 3145728u, 5242880u};

    const int seg  = blockIdx.x >> 3;
    const int nseg = blockIdx.x & 7;
    const int K    = Ks[seg];
    const int aoff = Aoff[seg];
    const unsigned short* Bs = B + Boff[seg];

    const int t    = threadIdx.x;
    const int lane = t & 63;
    const int w    = t >> 6;
    const int wm   = (w >> 1) * 64;
    const int wn   = (w & 1) * 64;
    const int lr   = lane & 15;
    const int quad = lane >> 4;

    const int blkM = blockIdx.y;

    const int e0 = t * 8;
    const int r0 = e0 >> 5;
    const int c0 = e0 & 31;

    const unsigned short* pa0 = A + (size_t)(blkM * TILE + r0) * NDIM + aoff + c0;
    const unsigned short* pa1 = pa0 + (size_t)64 * NDIM;
    const unsigned short* pb0 = Bs + (size_t)(nseg * TILE + r0) * K + c0;
    const unsigned short* pb1 = pb0 + (size_t)64 * K;

    unsigned short* dA0 = &lA[e0];
    unsigned short* dA1 = &lA[2048 + e0];
    unsigned short* dB0 = &lB[e0];
    unsigned short* dB1 = &lB[2048 + e0];

    const unsigned short* la0 = &lA[(wm + lr) * BK + quad * 8];
    const unsigned short* lb0 = &lB[(wn + lr) * BK + quad * 8];

    f32x4_t acc[4][4] = {};

    for (int k0 = 0; k0 < K; k0 += BK) {
        async_copy16(pa0 + k0, dA0);
        async_copy16(pa1 + k0, dA1);
        async_copy16(pb0 + k0, dB0);
        async_copy16(pb1 + k0, dB1);
        asm volatile("s_waitcnt vmcnt(0)" ::: "memory");
        __syncthreads();

        bf16x8_t af[4], bfr[4];
#pragma unroll
        for (int i = 0; i < 4; ++i)
            af[i] = *(const bf16x8_t*)(la0 + i * 16 * BK);
#pragma unroll
        for (int i = 0; i < 4; ++i)
            bfr[i] = *(const bf16x8_t*)(lb0 + i * 16 * BK);

#pragma unroll
        for (int mt = 0; mt < 4; ++mt)
#pragma unroll
            for (int nt = 0; nt < 4; ++nt)
                acc[mt][nt] = __builtin_amdgcn_mfma_f32_16x16x32_bf16(
                    af[mt], bfr[nt], acc[mt][nt], 0, 0, 0);

        __syncthreads();
    }

    const int orow0 = blkM * TILE + wm + quad * 4;
    const int ocol0 = seg * 1024 + nseg * TILE + wn + lr;
#pragma unroll
    for (int mt = 0; mt < 4; ++mt) {
#pragma unroll
        for (int r = 0; r < 4; ++r) {
            float* dst = C + (size_t)(orow0 + mt * 16 + r) * NDIM + ocol0;
#pragma unroll
            for (int nt = 0; nt < 4; ++nt)
                dst[nt * 16] = acc[mt][nt][r];
        }
    }
}

// ---- k4: in-place inverse transform on d_out ------------------------------
// One block owns one row b: read all components, barrier, write final layout.
// out_n = 0.25*(O0 + 2*Re(i^n*(Or+iOi)) + (-1)^n*O2)
__global__ __launch_bounds__(256) void post_kernel(float* __restrict__ O) {
    float* row = O + (size_t)blockIdx.x * NDIM;
    const int t = threadIdx.x;
    float v0[4], vr[4], vi[4], v2[4];
#pragma unroll
    for (int i = 0; i < 4; ++i) {
        int y = t + i * 256;
        v0[i] = row[y];
        vr[i] = row[1024 + y];
        vi[i] = row[2048 + y];
        v2[i] = row[3072 + y];
    }
    __syncthreads();
#pragma unroll
    for (int i = 0; i < 4; ++i) {
        int y = t + i * 256;
        float4 o;
        o.x = 0.25f * (v0[i] + 2.0f * vr[i] + v2[i]);
        o.y = 0.25f * (v0[i] - 2.0f * vi[i] - v2[i]);
        o.z = 0.25f * (v0[i] - 2.0f * vr[i] + v2[i]);
        o.w = 0.25f * (v0[i] + 2.0f * vi[i] - v2[i]);
        *(float4*)&row[4 * y] = o;
    }
}

extern "C" void kernel_launch(void* const* d_in, const int* in_sizes, int n_in,
                              void* d_out, int out_size, void* d_ws, size_t ws_size,
                              hipStream_t stream) {
    const float* x   = (const float*)d_in[0];   // (4096, 4096) fp32
    const float* eig = (const float*)d_in[1];   // (1024, 1024, 4) fp32
    float* out = (float*)d_out;

    unsigned short* Xp = (unsigned short*)d_ws;                    // 32 MiB
    unsigned short* Bp = Xp + (size_t)NDIM * NDIM;                 // 12 MiB

    fwd_x_kernel<<<(NDIM * 128) / 256, 256, 0, stream>>>(x, Xp);
    build_b_kernel<<<(1024 * 128) / 256, 256, 0, stream>>>(eig, Bp);

    dim3 grid(32, NDIM / TILE);                  // 32 N-blocks x 32 M-blocks
    gemm_seg_kernel<<<grid, 256, 0, stream>>>(Xp, Bp, out);

    post_kernel<<<NDIM, 256, 0, stream>>>(out);
}